// Round 3
// baseline (193.994 us; speedup 1.0000x reference)
//
#include <hip/hip_runtime.h>
#include <math.h>

// Problem constants (B=4, S=2048, H=1024, E=16, TOP_K=4)
constexpr int kTokens = 8192;   // B*S
constexpr int kH      = 1024;
constexpr int kE      = 16;
constexpr int kTopK   = 4;
constexpr int kNC     = 8;      // h-splits (128 h each): halves partials traffic vs 16

// ---------------------------------------------------------------------------
// Stage 1 v3: round-0's PROVEN pass structure (depth-1 register prefetch ->
// compute -> ds_write -> barrier), with the tile doubled to 64 tok x 64 h.
//
// Why: round-0 counters (54 us, VALUBusy 16.5%, HBM 17.5%, MfmaUtil 0) say
// latency/convoy-bound -- ~300 issue-cycles of compute per pass against
// 600-900 cycles of load latency, and 8 barriers/block convoying 4 waves.
// Doubling the tile doubles compute per barrier (256 FMA/lane ~ 600+ cycles,
// now actually covering the prefetch), halves barriers per unit work, and
// kNC=8 halves the partials round-trip while making the grid exactly
// 1024 blocks = 4 resident/CU (zero tail).
//
// Numerics = round-3-proven scheme: fp32 accum over 16-h chunks, fp64 fold
// every pass, block-level fp64 cross-wave reduce, fp32 partial per 128 h.
// Weight addresses depend only on (blockIdx, readfirstlane(wave)) ->
// wave-uniform -> scalar s_load path (proven: SGPR-only, no VMEM cost).
// ---------------------------------------------------------------------------
__global__ __launch_bounds__(256, 4)
void router_fmac(const float* __restrict__ x,   const float* __restrict__ img,
                 const float* __restrict__ txt, const float* __restrict__ aud,
                 const float* __restrict__ Wg,  const float* __restrict__ Wi,
                 const float* __restrict__ Wt,  const float* __restrict__ Wa,
                 float* __restrict__ partials)
{
    // 34.8 KB: two [64][68] tile buffers (stride 68 floats -> bank class
    // 68 mod 32 = 4, same conflict-free class as the proven stride 36).
    // Reused as red[4][64][20] (5120 floats) for the cross-wave reduce.
    __shared__ float smem[2 * 64 * 68];

    const int t  = threadIdx.x;
    const int w  = __builtin_amdgcn_readfirstlane(t >> 6);  // wave id (SGPR)
    const int ln = t & 63;                                  // lane = token
    const int hs    = blockIdx.x & 7;    // h-split 0..7
    const int tg    = blockIdx.x >> 3;   // token group 0..127
    const int tok0  = tg * 64;
    const int hbase = hs * 128;

    const float* Xs[4] = { x,  img, txt, aud };
    const float* Ws[4] = { Wg, Wi,  Wt,  Wa  };

    // staging role: rows sr, sr+16, sr+32, sr+48 ; float4-col sc (64-h tile)
    const int sc = t & 15;   // 0..15
    const int sr = t >> 4;   // 0..15

    // ---- prologue: stage pass 0 (modality 0, half 0) ----
    {
        const float* src = Xs[0] + (size_t)(tok0 + sr) * kH + hbase + sc * 4;
        const float4 v0 = *(const float4*)(src);
        const float4 v1 = *(const float4*)(src + (size_t)16 * kH);
        const float4 v2 = *(const float4*)(src + (size_t)32 * kH);
        const float4 v3 = *(const float4*)(src + (size_t)48 * kH);
        float* d = smem + sr * 68 + sc * 4;
        *(float4*)(d)           = v0;
        *(float4*)(d + 16 * 68) = v1;
        *(float4*)(d + 32 * 68) = v2;
        *(float4*)(d + 48 * 68) = v3;
    }
    __syncthreads();

    double dacc[kE];
#pragma unroll
    for (int e = 0; e < kE; ++e) dacc[e] = 0.0;

#pragma unroll
    for (int p = 0; p < 8; ++p) {        // pass = (modality p>>1, 64-h half p&1)
        const int m = p >> 1;
        const int s = p & 1;

        // depth-1 prefetch: next pass's 4 float4 rows, in flight during compute
        float4 n0, n1, n2, n3;
        if (p < 7) {
            const int m2 = (p + 1) >> 1, s2 = (p + 1) & 1;
            const float* src = Xs[m2] + (size_t)(tok0 + sr) * kH + hbase + s2 * 64 + sc * 4;
            n0 = *(const float4*)(src);
            n1 = *(const float4*)(src + (size_t)16 * kH);
            n2 = *(const float4*)(src + (size_t)32 * kH);
            n3 = *(const float4*)(src + (size_t)48 * kH);
        }

        // wave w computes its 16-h sub-slice of the 64-h tile (lane = token)
        float facc[kE];
#pragma unroll
        for (int e = 0; e < kE; ++e) facc[e] = 0.f;

        const float* buf = smem + (p & 1) * 4352 + ln * 68 + w * 16;
        const float* wb  = Ws[m] + (size_t)(hbase + s * 64 + w * 16) * kE; // wave-uniform

#pragma unroll
        for (int k4 = 0; k4 < 4; ++k4) {
            const float4 xv = *(const float4*)(buf + k4 * 4);
#pragma unroll
            for (int j = 0; j < 4; ++j) {
                const float xh = (j == 0) ? xv.x : (j == 1) ? xv.y : (j == 2) ? xv.z : xv.w;
                const float* wr = wb + (k4 * 4 + j) * kE;   // wave-uniform -> s_load
                const float4 w0 = *(const float4*)(wr + 0);
                const float4 w1 = *(const float4*)(wr + 4);
                const float4 w2 = *(const float4*)(wr + 8);
                const float4 w3 = *(const float4*)(wr + 12);
                facc[0]  += xh * w0.x;  facc[1]  += xh * w0.y;
                facc[2]  += xh * w0.z;  facc[3]  += xh * w0.w;
                facc[4]  += xh * w1.x;  facc[5]  += xh * w1.y;
                facc[6]  += xh * w1.z;  facc[7]  += xh * w1.w;
                facc[8]  += xh * w2.x;  facc[9]  += xh * w2.y;
                facc[10] += xh * w2.z;  facc[11] += xh * w2.w;
                facc[12] += xh * w3.x;  facc[13] += xh * w3.y;
                facc[14] += xh * w3.z;  facc[15] += xh * w3.w;
            }
        }

        // fold this 16-h fp32 chunk into the fp64 accumulator (every pass)
#pragma unroll
        for (int e = 0; e < kE; ++e) dacc[e] += (double)facc[e];

        // write prefetched tile into the other buffer; barrier ends the pass
        if (p < 7) {
            float* nbuf = smem + ((p + 1) & 1) * 4352 + sr * 68 + sc * 4;
            *(float4*)(nbuf)           = n0;
            *(float4*)(nbuf + 16 * 68) = n1;
            *(float4*)(nbuf + 32 * 68) = n2;
            *(float4*)(nbuf + 48 * 68) = n3;
        }
        __syncthreads();
    }

    // ---- cross-wave reduce: red[w][tok][e] (stride 20 floats, 16B-aligned) ----
#pragma unroll
    for (int q = 0; q < 4; ++q) {
        *(float4*)&smem[(w * 64 + ln) * 20 + q * 4] =
            make_float4((float)dacc[q * 4 + 0], (float)dacc[q * 4 + 1],
                        (float)dacc[q * 4 + 2], (float)dacc[q * 4 + 3]);
    }
    __syncthreads();
    {
        const int tok = t >> 2;
        const int eq  = t & 3;
        double s0 = 0.0, s1 = 0.0, s2 = 0.0, s3 = 0.0;
#pragma unroll
        for (int ww = 0; ww < 4; ++ww) {
            const float4 v = *(const float4*)&smem[(ww * 64 + tok) * 20 + eq * 4];
            s0 += (double)v.x;  s1 += (double)v.y;
            s2 += (double)v.z;  s3 += (double)v.w;
        }
        // coalesced float4 store of the fp32 partial [hs][tok][e]
        *(float4*)&partials[((size_t)hs * kTokens + tok0 + tok) * kE + eq * 4] =
            make_float4((float)s0, (float)s1, (float)s2, (float)s3);
    }
}

// ---------------------------------------------------------------------------
// Stage 2: combine 8 chunk-partials + biases (fp64), softmax, top-k, output
// writes, per-block expert sums. Block = 64 tokens x 256 threads.
// ---------------------------------------------------------------------------
__global__ __launch_bounds__(256)
void router_topk(const float* __restrict__ partials,
                 const float* __restrict__ bg, const float* __restrict__ bi,
                 const float* __restrict__ bt, const float* __restrict__ ba,
                 float* __restrict__ out, float* __restrict__ blocksum)
{
    __shared__ double lgs[64][kE + 1];
    __shared__ float  pr[64][kE + 1];

    const int t    = threadIdx.x;
    const int tq   = t >> 2;      // token offset 0..63
    const int eq   = t & 3;       // e-quad
    const int tok0 = blockIdx.x * 64;

    double a0 = (double)bg[eq*4+0] + (double)bi[eq*4+0] + (double)bt[eq*4+0] + (double)ba[eq*4+0];
    double a1 = (double)bg[eq*4+1] + (double)bi[eq*4+1] + (double)bt[eq*4+1] + (double)ba[eq*4+1];
    double a2 = (double)bg[eq*4+2] + (double)bi[eq*4+2] + (double)bt[eq*4+2] + (double)ba[eq*4+2];
    double a3 = (double)bg[eq*4+3] + (double)bi[eq*4+3] + (double)bt[eq*4+3] + (double)ba[eq*4+3];

#pragma unroll
    for (int c = 0; c < kNC; ++c) {
        const float4 v = *(const float4*)(partials + ((size_t)c * kTokens + tok0 + tq) * kE + eq * 4);
        a0 += (double)v.x;  a1 += (double)v.y;  a2 += (double)v.z;  a3 += (double)v.w;
    }
    lgs[tq][eq*4+0] = a0;  lgs[tq][eq*4+1] = a1;
    lgs[tq][eq*4+2] = a2;  lgs[tq][eq*4+3] = a3;
    __syncthreads();

    if (t < 64) {
        const int tok = tok0 + t;
        double lg[kE];
#pragma unroll
        for (int e = 0; e < kE; ++e) lg[e] = lgs[t][e];

        double mx = lg[0];
#pragma unroll
        for (int e = 1; e < kE; ++e) mx = fmax(mx, lg[e]);

        float p[kE];
        float sum = 0.f;
#pragma unroll
        for (int e = 0; e < kE; ++e) {
            p[e] = expf((float)(lg[e] - mx));
            sum += p[e];
        }
        const float inv = 1.f / sum;
#pragma unroll
        for (int e = 0; e < kE; ++e) { p[e] *= inv; pr[t][e] = p[e]; }

        // top-4, descending, ties -> smallest index (matches jax.lax.top_k)
        unsigned used = 0;
        float tp[kTopK];
        int   ti[kTopK];
        float s4 = 0.f;
#pragma unroll
        for (int k = 0; k < kTopK; ++k) {
            float best = -1.f;
            int   bidx = 0;
#pragma unroll
            for (int e = 0; e < kE; ++e) {
                if (!((used >> e) & 1u) && p[e] > best) { best = p[e]; bidx = e; }
            }
            used |= 1u << bidx;
            tp[k] = best;
            ti[k] = bidx;
            s4 += best;
        }
        const float rn = 1.f / s4;

        *(float4*)&out[(size_t)tok * kTopK] =
            make_float4((float)ti[0], (float)ti[1], (float)ti[2], (float)ti[3]);
        *(float4*)&out[(size_t)kTokens * kTopK + (size_t)tok * kTopK] =
            make_float4(tp[0] * rn, tp[1] * rn, tp[2] * rn, tp[3] * rn);
    }
    __syncthreads();

    if (t < kE) {
        float s = 0.f;
#pragma unroll
        for (int tk = 0; tk < 64; ++tk) s += pr[tk][t];
        blocksum[blockIdx.x * kE + t] = s;
    }
}

// ---------------------------------------------------------------------------
// Stage 3 v2: parallel 128-block-partial reduce -> mean prob -> aux scalar.
// 128 threads x 16 coalesced loads + fp64 LDS tree. Deterministic.
// ---------------------------------------------------------------------------
__global__ __launch_bounds__(256)
void router_aux(const float* __restrict__ blocksum, float* __restrict__ out)
{
    __shared__ double ps[8][kE];
    __shared__ double fin[kE];
    const int t = threadIdx.x;
    if (t < 128) {
        const int e  = t & 15;
        const int bq = t >> 4;   // 0..7
        double s = 0.0;
#pragma unroll
        for (int k = 0; k < 16; ++k)
            s += (double)blocksum[(bq * 16 + k) * kE + e];
        ps[bq][e] = s;
    }
    __syncthreads();
    if (t < kE) {
        double s = 0.0;
#pragma unroll
        for (int q = 0; q < 8; ++q) s += ps[q][t];
        fin[t] = s / (double)kTokens;
    }
    __syncthreads();
    if (t == 0) {
        double aux = 0.0;
#pragma unroll
        for (int e = 0; e < kE; ++e) aux += fin[e] * log(fin[e] * (double)kE + 1e-9);
        out[(size_t)kTokens * kTopK * 2] = (float)aux;  // element 65536
    }
}

extern "C" void kernel_launch(void* const* d_in, const int* in_sizes, int n_in,
                              void* d_out, int out_size, void* d_ws, size_t ws_size,
                              hipStream_t stream)
{
    const float* x   = (const float*)d_in[0];
    const float* img = (const float*)d_in[1];
    const float* txt = (const float*)d_in[2];
    const float* aud = (const float*)d_in[3];
    const float* Wg  = (const float*)d_in[4];
    const float* bg  = (const float*)d_in[5];
    const float* Wi  = (const float*)d_in[6];
    const float* bi  = (const float*)d_in[7];
    const float* Wt  = (const float*)d_in[8];
    const float* bt  = (const float*)d_in[9];
    const float* Wa  = (const float*)d_in[10];
    const float* ba  = (const float*)d_in[11];

    float* out      = (float*)d_out;
    float* partials = (float*)d_ws;   // 8*8192*16*4 = 4 MB (ws >= 8.4 MB proven)
    float* blocksum = (float*)((char*)d_ws + (size_t)kNC * kTokens * kE * 4);  // 8 KB

    router_fmac<<<1024, 256, 0, stream>>>(x, img, txt, aud, Wg, Wi, Wt, Wa, partials);
    router_topk<<<128, 256, 0, stream>>>(partials, bg, bi, bt, ba, out, blocksum);
    router_aux<<<1, 256, 0, stream>>>(blocksum, out);
}

// Round 4
// 187.416 us; speedup vs baseline: 1.0351x; 1.0351x over previous
//
#include <hip/hip_runtime.h>
#include <math.h>

// Problem constants (B=4, S=2048, H=1024, E=16, TOP_K=4)
constexpr int kTokens = 8192;   // B*S
constexpr int kH      = 1024;
constexpr int kE      = 16;
constexpr int kTopK   = 4;
constexpr int kNC     = 16;     // h-splits (64 h each) -- round-0 proven geometry

// ---------------------------------------------------------------------------
// Stage 1 v4: BARRIER-FREE pass loop via wave-private staging.
//
// Post-mortem r3: doubling per-barrier compute made it 2x WORSE (54->98us,
// VALUBusy 20%, HBM 10.7%) -- throughput tracks block TLP, not per-barrier
// work. Diagnosis: the per-pass __syncthreads() convoys 4 waves onto the
// slowest prefetch return. Fix: wave w stages ONLY its own 8-h slice into a
// wave-private LDS region -> no cross-wave dependency -> no barriers in the
// loop. Same-wave ds_write->ds_read ordered by s_waitcnt lgkmcnt(0) fence
// (+sched_barrier(0), rule 18); DS ops from one wave complete in order.
// Geometry/numerics = round-0 proven: 2048 blocks (128 tg x 16 hs), 8 passes
// of 32-h half-tiles, 128 FMA/lane/pass, wave-uniform s_load weights, fp32
// accum over 16-h chunks folded to fp64 every 2 passes, fp64 cross-wave
// reduce (one epilogue barrier pair only), fp32 partial per 64 h.
// ---------------------------------------------------------------------------
__global__ __launch_bounds__(256, 5)
void router_fmac(const float* __restrict__ x,   const float* __restrict__ img,
                 const float* __restrict__ txt, const float* __restrict__ aud,
                 const float* __restrict__ Wg,  const float* __restrict__ Wi,
                 const float* __restrict__ Wt,  const float* __restrict__ Wa,
                 float* __restrict__ partials)
{
    // 24 KB: wave-private double-buffered tiles [buf2][wave4][64 rows][12].
    // Row stride 12 floats: 12*ln mod 32 has period 8 -> same measured-ok
    // bank class as the proven stride-36. Epilogue reuses words 0..5119 as
    // red[4][64][20] (after a real barrier).
    __shared__ float smem[2 * 4 * 64 * 12];   // 6144 floats

    const int t  = threadIdx.x;
    const int w  = __builtin_amdgcn_readfirstlane(t >> 6);  // wave id (SGPR)
    const int ln = t & 63;                                  // lane = token
    const int hs    = blockIdx.x & 15;   // h-split
    const int tg    = blockIdx.x >> 4;   // token group
    const int tok0  = tg * 64;
    const int hbase = hs * 64;

    const float* Xs[4] = { x,  img, txt, aud };
    const float* Ws[4] = { Wg, Wi,  Wt,  Wa  };

    // wave-private staging: lane covers (row rA, float4 c2) and row rA+32
    // of THIS wave's 8-float column slice. Global: 32-B segments per row
    // (the other half of each 64-B line is the sibling wave's slice -> L1).
    const int c2 = ln & 1;
    const int rA = ln >> 1;   // 0..31

    float* wbuf0 = smem + w * 768;           // this wave's buffer-0 region
    float* wbuf1 = smem + 3072 + w * 768;    // buffer-1 region

    // ---- prologue: stage pass 0 (modality 0, half 0) into buffer 0 ----
    {
        const float* src = Xs[0] + (size_t)(tok0 + rA) * kH + hbase + w * 8 + c2 * 4;
        const float4 va = *(const float4*)(src);
        const float4 vb = *(const float4*)(src + (size_t)32 * kH);
        *(float4*)&wbuf0[rA * 12 + c2 * 4]        = va;
        *(float4*)&wbuf0[(rA + 32) * 12 + c2 * 4] = vb;
    }
    asm volatile("s_waitcnt lgkmcnt(0)" ::: "memory");  // own writes retired
    __builtin_amdgcn_sched_barrier(0);

    double dacc[kE];
#pragma unroll
    for (int e = 0; e < kE; ++e) dacc[e] = 0.0;
    float facc[kE];

#pragma unroll
    for (int p = 0; p < 8; ++p) {        // pass = (modality p>>1, half p&1)
        const int m = p >> 1;
        const int s = p & 1;

        // register prefetch of next pass's slice (in flight during compute)
        float4 na, nb;
        if (p < 7) {
            const int m2 = (p + 1) >> 1, s2 = (p + 1) & 1;
            const float* src = Xs[m2] + (size_t)(tok0 + rA) * kH + hbase + s2 * 32 + w * 8 + c2 * 4;
            na = *(const float4*)(src);
            nb = *(const float4*)(src + (size_t)32 * kH);
        }

        if (s == 0) {
#pragma unroll
            for (int e = 0; e < kE; ++e) facc[e] = 0.f;
        }

        const float* buf   = (p & 1) ? wbuf1 : wbuf0;
        const float* wbase = Ws[m] + (size_t)(hbase + s * 32 + w * 8) * kE; // wave-uniform

#pragma unroll
        for (int k4 = 0; k4 < 2; ++k4) {
            const float4 xv = *(const float4*)&buf[ln * 12 + k4 * 4];
#pragma unroll
            for (int j = 0; j < 4; ++j) {
                const float xh = (j == 0) ? xv.x : (j == 1) ? xv.y : (j == 2) ? xv.z : xv.w;
                const float* wr = wbase + (k4 * 4 + j) * kE;   // wave-uniform -> s_load
                const float4 w0 = *(const float4*)(wr + 0);
                const float4 w1 = *(const float4*)(wr + 4);
                const float4 w2 = *(const float4*)(wr + 8);
                const float4 w3 = *(const float4*)(wr + 12);
                facc[0]  += xh * w0.x;  facc[1]  += xh * w0.y;
                facc[2]  += xh * w0.z;  facc[3]  += xh * w0.w;
                facc[4]  += xh * w1.x;  facc[5]  += xh * w1.y;
                facc[6]  += xh * w1.z;  facc[7]  += xh * w1.w;
                facc[8]  += xh * w2.x;  facc[9]  += xh * w2.y;
                facc[10] += xh * w2.z;  facc[11] += xh * w2.w;
                facc[12] += xh * w3.x;  facc[13] += xh * w3.y;
                facc[14] += xh * w3.z;  facc[15] += xh * w3.w;
            }
        }

        if (s == 1) {   // fold 16-h fp32 chunk into fp64
#pragma unroll
            for (int e = 0; e < kE; ++e) dacc[e] += (double)facc[e];
        }

        // write prefetched slice into the other private buffer; fence only
        if (p < 7) {
            float* nbuf = (p & 1) ? wbuf0 : wbuf1;
            *(float4*)&nbuf[rA * 12 + c2 * 4]        = na;
            *(float4*)&nbuf[(rA + 32) * 12 + c2 * 4] = nb;
        }
        asm volatile("s_waitcnt lgkmcnt(0)" ::: "memory");  // wave-local order
        __builtin_amdgcn_sched_barrier(0);
    }

    // ---- epilogue: cross-wave fp64 reduce (the only real barriers) ----
    __syncthreads();   // all waves done with private buffers before overwrite
#pragma unroll
    for (int q = 0; q < 4; ++q) {
        *(float4*)&smem[(w * 64 + ln) * 20 + q * 4] =
            make_float4((float)dacc[q * 4 + 0], (float)dacc[q * 4 + 1],
                        (float)dacc[q * 4 + 2], (float)dacc[q * 4 + 3]);
    }
    __syncthreads();
    {
        const int tok = t >> 2;
        const int eq  = t & 3;
        double s0 = 0.0, s1 = 0.0, s2 = 0.0, s3 = 0.0;
#pragma unroll
        for (int ww = 0; ww < 4; ++ww) {
            const float4 v = *(const float4*)&smem[(ww * 64 + tok) * 20 + eq * 4];
            s0 += (double)v.x;  s1 += (double)v.y;
            s2 += (double)v.z;  s3 += (double)v.w;
        }
        *(float4*)&partials[((size_t)hs * kTokens + tok0 + tok) * kE + eq * 4] =
            make_float4((float)s0, (float)s1, (float)s2, (float)s3);
    }
}

// ---------------------------------------------------------------------------
// Stage 2 v2: 256 blocks x 32 tokens (was 128 blocks = half the GPU idle).
// Thread (tq, eq, hc): sums 8 of the 16 chunk-partials for its e-quad;
// fp64 halves combined deterministically in LDS. Softmax/top-k unchanged.
// ---------------------------------------------------------------------------
__global__ __launch_bounds__(256)
void router_topk(const float* __restrict__ partials,
                 const float* __restrict__ bg, const float* __restrict__ bi,
                 const float* __restrict__ bt, const float* __restrict__ ba,
                 float* __restrict__ out, float* __restrict__ blocksum)
{
    __shared__ double lgs[32][2][kE + 2];
    __shared__ float  pr[32][kE + 1];

    const int t    = threadIdx.x;
    const int tq   = t >> 3;        // token 0..31
    const int eq   = (t >> 1) & 3;  // e-quad
    const int hc   = t & 1;         // chunk half (c 0..7 vs 8..15)
    const int tok0 = blockIdx.x * 32;

    double a0 = 0.0, a1 = 0.0, a2 = 0.0, a3 = 0.0;
    if (hc == 0) {  // biases added exactly once, in the low half
        a0 = (double)bg[eq*4+0] + (double)bi[eq*4+0] + (double)bt[eq*4+0] + (double)ba[eq*4+0];
        a1 = (double)bg[eq*4+1] + (double)bi[eq*4+1] + (double)bt[eq*4+1] + (double)ba[eq*4+1];
        a2 = (double)bg[eq*4+2] + (double)bi[eq*4+2] + (double)bt[eq*4+2] + (double)ba[eq*4+2];
        a3 = (double)bg[eq*4+3] + (double)bi[eq*4+3] + (double)bt[eq*4+3] + (double)ba[eq*4+3];
    }

#pragma unroll
    for (int c8 = 0; c8 < 8; ++c8) {
        const int c = hc * 8 + c8;
        const float4 v = *(const float4*)(partials + ((size_t)c * kTokens + tok0 + tq) * kE + eq * 4);
        a0 += (double)v.x;  a1 += (double)v.y;  a2 += (double)v.z;  a3 += (double)v.w;
    }
    lgs[tq][hc][eq*4+0] = a0;  lgs[tq][hc][eq*4+1] = a1;
    lgs[tq][hc][eq*4+2] = a2;  lgs[tq][hc][eq*4+3] = a3;
    __syncthreads();

    if (t < 32) {
        const int tok = tok0 + t;
        double lg[kE];
#pragma unroll
        for (int e = 0; e < kE; ++e) lg[e] = lgs[t][0][e] + lgs[t][1][e];

        double mx = lg[0];
#pragma unroll
        for (int e = 1; e < kE; ++e) mx = fmax(mx, lg[e]);

        float p[kE];
        float sum = 0.f;
#pragma unroll
        for (int e = 0; e < kE; ++e) {
            p[e] = expf((float)(lg[e] - mx));
            sum += p[e];
        }
        const float inv = 1.f / sum;
#pragma unroll
        for (int e = 0; e < kE; ++e) { p[e] *= inv; pr[t][e] = p[e]; }

        // top-4, descending, ties -> smallest index (matches jax.lax.top_k)
        unsigned used = 0;
        float tp[kTopK];
        int   ti[kTopK];
        float s4 = 0.f;
#pragma unroll
        for (int k = 0; k < kTopK; ++k) {
            float best = -1.f;
            int   bidx = 0;
#pragma unroll
            for (int e = 0; e < kE; ++e) {
                if (!((used >> e) & 1u) && p[e] > best) { best = p[e]; bidx = e; }
            }
            used |= 1u << bidx;
            tp[k] = best;
            ti[k] = bidx;
            s4 += best;
        }
        const float rn = 1.f / s4;

        *(float4*)&out[(size_t)tok * kTopK] =
            make_float4((float)ti[0], (float)ti[1], (float)ti[2], (float)ti[3]);
        *(float4*)&out[(size_t)kTokens * kTopK + (size_t)tok * kTopK] =
            make_float4(tp[0] * rn, tp[1] * rn, tp[2] * rn, tp[3] * rn);
    }
    __syncthreads();

    if (t < kE) {
        float s = 0.f;
#pragma unroll
        for (int tk = 0; tk < 32; ++tk) s += pr[tk][t];
        blocksum[blockIdx.x * kE + t] = s;
    }
}

// ---------------------------------------------------------------------------
// Stage 3 v3: 256 block-partials -> mean prob per expert -> aux loss scalar.
// 256 threads x 16 coalesced loads + fp64 LDS tree. Deterministic.
// ---------------------------------------------------------------------------
__global__ __launch_bounds__(256)
void router_aux(const float* __restrict__ blocksum, float* __restrict__ out)
{
    __shared__ double ps[16][kE];
    __shared__ double fin[kE];
    const int t = threadIdx.x;
    {
        const int e  = t & 15;
        const int bq = t >> 4;   // 0..15
        double s = 0.0;
#pragma unroll
        for (int k = 0; k < 16; ++k)
            s += (double)blocksum[(bq * 16 + k) * kE + e];
        ps[bq][e] = s;
    }
    __syncthreads();
    if (t < kE) {
        double s = 0.0;
#pragma unroll
        for (int q = 0; q < 16; ++q) s += ps[q][t];
        fin[t] = s / (double)kTokens;
    }
    __syncthreads();
    if (t == 0) {
        double aux = 0.0;
#pragma unroll
        for (int e = 0; e < kE; ++e) aux += fin[e] * log(fin[e] * (double)kE + 1e-9);
        out[(size_t)kTokens * kTopK * 2] = (float)aux;  // element 65536
    }
}

extern "C" void kernel_launch(void* const* d_in, const int* in_sizes, int n_in,
                              void* d_out, int out_size, void* d_ws, size_t ws_size,
                              hipStream_t stream)
{
    const float* x   = (const float*)d_in[0];
    const float* img = (const float*)d_in[1];
    const float* txt = (const float*)d_in[2];
    const float* aud = (const float*)d_in[3];
    const float* Wg  = (const float*)d_in[4];
    const float* bg  = (const float*)d_in[5];
    const float* Wi  = (const float*)d_in[6];
    const float* bi  = (const float*)d_in[7];
    const float* Wt  = (const float*)d_in[8];
    const float* bt  = (const float*)d_in[9];
    const float* Wa  = (const float*)d_in[10];
    const float* ba  = (const float*)d_in[11];

    float* out      = (float*)d_out;
    float* partials = (float*)d_ws;   // 16*8192*16*4 = 8 MB (ws >= 8.4 MB proven)
    float* blocksum = (float*)((char*)d_ws + (size_t)kNC * kTokens * kE * 4);  // 16 KB

    router_fmac<<<2048, 256, 0, stream>>>(x, img, txt, aud, Wg, Wi, Wt, Wa, partials);
    router_topk<<<256, 256, 0, stream>>>(partials, bg, bi, bt, ba, out, blocksum);
    router_aux<<<1, 256, 0, stream>>>(blocksum, out);
}